// Round 6
// baseline (125.422 us; speedup 1.0000x reference)
//
#include <hip/hip_runtime.h>
#include <hip/hip_bf16.h>

// ScoreNet fused: central moments -> MLP -> analytic jacobian contraction.
// Round 6: r5 (fewer/wider weight loads, deeper prefetch) was NEUTRAL ->
// bottleneck is BYTES from a hot 32KB L2 set (W2a re-fetched per wave:
// 8192 x 32KB = 256MB through ~128 L2 lines = channel camping, ~7 TB/s eff).
// Fix: stage all weights in LDS once per block, 16 samples/block (4/wave loop)
// -> global weight traffic 256MB -> 16MB; hot loop reads LDS + registers.

static __device__ __forceinline__ float gelu_f(float x) {
    // Abramowitz-Stegun 7.1.26 erf (max err 1.5e-7), branch-free.
    float y = 0.7071067811865475f * x;
    float s = fabsf(y);
    float t = __builtin_amdgcn_rcpf(fmaf(0.3275911f, s, 1.0f));
    float p = t * fmaf(t, fmaf(t, fmaf(t, fmaf(t, 1.061405429f,
                    -1.453152027f), 1.421413741f), -0.284496736f), 0.254829592f);
    float e = __expf(-y * y);
    float ea = fmaf(-p, e, 1.0f);
    float erfv = copysignf(ea, y);
    return 0.5f * x * (1.0f + erfv);
}

// Wave64 sum via DPP row_shr 1/2/4/8 + row_bcast 15/31 (r4 win: zero DS ops);
// total lands in lane 63, broadcast back via readlane (wave-uniform SGPR).
#define DPP_ADD(v, ctrl) \
    v += __int_as_float(__builtin_amdgcn_update_dpp(0, __float_as_int(v), ctrl, 0xf, 0xf, true))

static __device__ __forceinline__ float wave_sum(float v) {
    DPP_ADD(v, 0x111);  // row_shr:1
    DPP_ADD(v, 0x112);  // row_shr:2
    DPP_ADD(v, 0x114);  // row_shr:4
    DPP_ADD(v, 0x118);  // row_shr:8
    DPP_ADD(v, 0x142);  // row_bcast:15
    DPP_ADD(v, 0x143);  // row_bcast:31
    return __int_as_float(__builtin_amdgcn_readlane(__float_as_int(v), 63));
}

static __device__ __forceinline__ float bcast_lane(float v, int l) {
    return __int_as_float(__builtin_amdgcn_readlane(__float_as_int(v), l));
}

#define TWO_PI_F 6.283185307179586f
#define SAMPLES_PER_BLOCK 16

__global__ __launch_bounds__(256, 2) void scorenet_fused(
    const float* __restrict__ x,      // [B,100,2]
    const float* __restrict__ t_in,   // [1]
    const float* __restrict__ Wf,     // [32]
    const float* __restrict__ embW,   // [64,64]
    const float* __restrict__ embB,   // [64]
    const float* __restrict__ W1,     // [12,64]
    const float* __restrict__ b1,     // [64]
    const float* __restrict__ W2a,    // [64,128]
    const float* __restrict__ b2a,    // [128]
    const float* __restrict__ W2b,    // [128,12]
    const float* __restrict__ b2b,    // [12]
    const float* __restrict__ W2c,    // [12,12]
    const float* __restrict__ b2c,    // [12]
    float* __restrict__ out,          // [B,100,2]
    int B)
{
    __shared__ __align__(16) float s_W2a[8192];   // [64][128]
    __shared__ __align__(16) float s_W2b[1536];   // [128][12]
    __shared__ __align__(16) float s_W1[768];     // [12][64]
    __shared__ __align__(16) float s_W2c[144];    // [12][12]
    __shared__ __align__(16) float s_b1[64];
    __shared__ __align__(16) float s_b2a[128];
    __shared__ __align__(16) float s_b2b[12];
    __shared__ __align__(16) float s_b2c[12];
    __shared__ __align__(16) float s_f[64];
    __shared__ float s_emb[64];

    const int tid = threadIdx.x;
    const float tval = t_in[0];

    // ---- cooperative weight staging (once per block; 512 blocks x 44KB)
    for (int i = tid; i < 2048; i += 256) ((float4*)s_W2a)[i] = ((const float4*)W2a)[i];
    for (int i = tid; i < 384;  i += 256) ((float4*)s_W2b)[i] = ((const float4*)W2b)[i];
    for (int i = tid; i < 192;  i += 256) ((float4*)s_W1)[i]  = ((const float4*)W1)[i];
    for (int i = tid; i < 36;   i += 256) ((float4*)s_W2c)[i] = ((const float4*)W2c)[i];
    for (int i = tid; i < 16;   i += 256) ((float4*)s_b1)[i]  = ((const float4*)b1)[i];
    for (int i = tid; i < 32;   i += 256) ((float4*)s_b2a)[i] = ((const float4*)b2a)[i];
    for (int i = tid; i < 3;    i += 256) ((float4*)s_b2b)[i] = ((const float4*)b2b)[i];
    for (int i = tid; i < 3;    i += 256) ((float4*)s_b2c)[i] = ((const float4*)b2c)[i];
    if (tid >= 224) {
        int i = tid - 224;
        float xp = tval * Wf[i] * TWO_PI_F;
        s_f[i]      = sinf(xp);
        s_f[i + 32] = cosf(xp);
    }
    __syncthreads();

    // ---- Gaussian-Fourier time embedding (sample-independent), once per block.
    if (tid < 64) {
        float acc = embB[tid];
        const float4* f4 = reinterpret_cast<const float4*>(s_f);
        #pragma unroll
        for (int c = 0; c < 16; ++c) {
            float4 a4 = f4[c];
            int j = 4 * c;
            acc = fmaf(a4.x, embW[(j+0)*64 + tid],
                  fmaf(a4.y, embW[(j+1)*64 + tid],
                  fmaf(a4.z, embW[(j+2)*64 + tid],
                  fmaf(a4.w, embW[(j+3)*64 + tid], acc))));
        }
        s_emb[tid] = acc;
    }
    __syncthreads();

    const int lane = tid & 63;
    const int wv = tid >> 6;
    const bool has2 = lane < 36;

    // ---- hoist loop-invariant lane-owned weights into registers
    float wb[24];                      // W2b rows 2l, 2l+1
    #pragma unroll
    for (int k = 0; k < 24; ++k) wb[k] = s_W2b[lane * 24 + k];
    float w1c[12];                     // W1 column `lane`
    #pragma unroll
    for (int k = 0; k < 12; ++k) w1c[k] = s_W1[k * 64 + lane];
    float b2bv[12];
    #pragma unroll
    for (int k = 0; k < 12; ++k) b2bv[k] = s_b2b[k];
    const int kk = lane < 12 ? lane : 0;   // lane k owns h[k]
    float w2ck[12];                    // W2c column kk
    #pragma unroll
    for (int j = 0; j < 12; ++j) w2ck[j] = s_W2c[j * 12 + kk];
    const float b2ck = s_b2c[kk];
    const float b1v  = s_b1[lane];
    const float b2aE = s_b2a[2 * lane], b2aO = s_b2a[2 * lane + 1];
    const float embv = s_emb[lane];
    const float rst  = rsqrtf(tval);

    const int b0 = blockIdx.x * SAMPLES_PER_BLOCK + wv * 4;

    // ---- prefetch x for this wave's 4 samples (contiguous 3.2KB)
    float2 P0[4], P1[4];
    #pragma unroll
    for (int s = 0; s < 4; ++s) {
        int bs = b0 + s; if (bs >= B) bs = B - 1;
        const float2* px = reinterpret_cast<const float2*>(x) + (size_t)bs * 100;
        P0[s] = px[lane];
        P1[s] = px[has2 ? lane + 64 : lane];
    }

    for (int s = 0; s < 4; ++s) {
        const int b = b0 + s;

        float xa = P0[s].x, ya = P0[s].y;
        float xb = has2 ? P1[s].x : 0.0f;
        float yb = has2 ? P1[s].y : 0.0f;

        // ---- mean over 100 points
        const float mux = wave_sum(xa + xb) * 0.01f;
        const float muy = wave_sum(ya + yb) * 0.01f;

        float ua = xa - mux, va = ya - muy;
        float ub = has2 ? (xb - mux) : 0.0f;
        float vb = has2 ? (yb - muy) : 0.0f;

        // ---- 12 central-moment monomial sums
        // order: (1,1)(2,0)(0,2)(2,1)(1,2)(3,0)(0,3)(2,2)(3,1)(1,3)(4,0)(0,4)
        float ms[12];
        {
            float u2 = ua * ua, v2 = va * va;
            ms[0] = ua * va;   ms[1] = u2;        ms[2] = v2;
            ms[3] = u2 * va;   ms[4] = ua * v2;
            ms[5] = u2 * ua;   ms[6] = v2 * va;
            ms[7] = u2 * v2;   ms[8] = ms[5] * va; ms[9] = ua * ms[6];
            ms[10] = u2 * u2;  ms[11] = v2 * v2;
            float w2 = ub * ub, z2 = vb * vb;
            ms[0] += ub * vb;  ms[1] += w2;       ms[2] += z2;
            ms[3] += w2 * vb;  ms[4] += ub * z2;
            ms[5] += w2 * ub;  ms[6] += z2 * vb;
            ms[7] += w2 * z2;  ms[8] += w2 * ub * vb; ms[9] += ub * z2 * vb;
            ms[10] += w2 * w2; ms[11] += z2 * z2;
        }
        float m[12];   // wave-uniform after DPP reduction
        #pragma unroll
        for (int k = 0; k < 12; ++k) m[k] = wave_sum(ms[k]);

        // ---- h1 = gelu(m @ W1 + b1); lane owns unit `lane` (weights in regs)
        float a1 = b1v;
        #pragma unroll
        for (int k = 0; k < 12; ++k) a1 = fmaf(m[k], w1c[k], a1);
        float aval = gelu_f(a1) + embv;

        // ---- h2 = gelu((h1+emb) @ W2a + b2a); lane owns units (2l, 2l+1).
        // aval broadcast via readlane; W2a from LDS (ds_read_b64), even/odd
        // split -> two independent 32-deep FMA chains per unit.
        const float2* w2a2 = reinterpret_cast<const float2*>(s_W2a);
        float accE0 = b2aE, accO0 = b2aO;
        float accE1 = 0.0f, accO1 = 0.0f;
        #pragma unroll
        for (int j = 0; j < 64; j += 2) {
            float aj0 = bcast_lane(aval, j);
            float aj1 = bcast_lane(aval, j + 1);
            float2 w0  = w2a2[j * 64 + lane];
            float2 w1v = w2a2[(j + 1) * 64 + lane];
            accE0 = fmaf(aj0, w0.x,  accE0);
            accO0 = fmaf(aj0, w0.y,  accO0);
            accE1 = fmaf(aj1, w1v.x, accE1);
            accO1 = fmaf(aj1, w1v.y, accO1);
        }
        float h2e = gelu_f(accE0 + accE1);   // unit 2l
        float h2o = gelu_f(accO0 + accO1);   // unit 2l+1

        // ---- h3 = gelu(h2 @ W2b + b2b): per-lane partials (regs) + DPP
        float h3[12];  // wave-uniform
        #pragma unroll
        for (int k = 0; k < 12; ++k) {
            float p3 = fmaf(h2e, wb[k], h2o * wb[12 + k]);
            h3[k] = gelu_f(wave_sum(p3) + b2bv[k]);
        }

        // ---- h = (h3 @ W2c + b2c)/sqrt(t): lane k computes h[k], broadcast.
        float acch = b2ck;
        #pragma unroll
        for (int j = 0; j < 12; ++j) acch = fmaf(h3[j], w2ck[j], acch);
        acch *= rst;
        float h[12];
        #pragma unroll
        for (int k = 0; k < 12; ++k) h[k] = bcast_lane(acch, k);

        // ---- per-sample correction constants (mean-shift jacobian term)
        const float inv_n = 0.01f;
        float c0 = (2.0f*h[3]*m[0] + h[4]*m[2] + 3.0f*h[5]*m[1] + 2.0f*h[7]*m[4]
                  + 3.0f*h[8]*m[3] + h[9]*m[6] + 4.0f*h[10]*m[5]) * inv_n;
        float c1 = (h[3]*m[1] + 2.0f*h[4]*m[0] + 3.0f*h[6]*m[2] + 2.0f*h[7]*m[3]
                  + h[8]*m[5] + 3.0f*h[9]*m[4] + 4.0f*h[11]*m[6]) * inv_n;

        // cubic polynomial coefficients in (u, v) — wave-uniform
        const float A1 = 2.0f*h[1], A2 = h[0],      A3 = 3.0f*h[5], A4 = 2.0f*h[3], A5 = h[4];
        const float A6 = 4.0f*h[10],A7 = 3.0f*h[8], A8 = 2.0f*h[7], A9 = h[9];
        const float B1 = h[0],      B2 = 2.0f*h[2], B3 = h[3],      B4 = 2.0f*h[4], B5 = 3.0f*h[6];
        const float B6 = h[8],      B7 = 2.0f*h[7], B8 = 3.0f*h[9], B9 = 4.0f*h[11];

        if (b < B) {
            float2* pout = reinterpret_cast<float2*>(out) + (size_t)b * 100;
            {
                float u = ua, v = va;
                float u2 = u*u, v2 = v*v;
                float o0 = A1*u + A2*v + A3*u2 + A4*u*v + A5*v2 + A6*u2*u + A7*u2*v + A8*u*v2 + A9*v2*v - c0;
                float o1 = B1*u + B2*v + B3*u2 + B4*u*v + B5*v2 + B6*u2*u + B7*u2*v + B8*u*v2 + B9*v2*v - c1;
                float2 r; r.x = o0; r.y = o1;
                pout[lane] = r;
            }
            if (has2) {
                float u = ub, v = vb;
                float u2 = u*u, v2 = v*v;
                float o0 = A1*u + A2*v + A3*u2 + A4*u*v + A5*v2 + A6*u2*u + A7*u2*v + A8*u*v2 + A9*v2*v - c0;
                float o1 = B1*u + B2*v + B3*u2 + B4*u*v + B5*v2 + B6*u2*u + B7*u2*v + B8*u*v2 + B9*v2*v - c1;
                float2 r; r.x = o0; r.y = o1;
                pout[lane + 64] = r;
            }
        }
    }
}

extern "C" void kernel_launch(void* const* d_in, const int* in_sizes, int n_in,
                              void* d_out, int out_size, void* d_ws, size_t ws_size,
                              hipStream_t stream) {
    const float* x    = (const float*)d_in[0];
    const float* t    = (const float*)d_in[1];
    // d_in[2] = K (exponent table) — baked into the kernel as compile-time constants.
    const float* Wf   = (const float*)d_in[3];
    const float* embW = (const float*)d_in[4];
    const float* embB = (const float*)d_in[5];
    const float* W1   = (const float*)d_in[6];
    const float* b1   = (const float*)d_in[7];
    const float* W2a  = (const float*)d_in[8];
    const float* b2a  = (const float*)d_in[9];
    const float* W2b  = (const float*)d_in[10];
    const float* b2b  = (const float*)d_in[11];
    const float* W2c  = (const float*)d_in[12];
    const float* b2c  = (const float*)d_in[13];

    const int B = in_sizes[0] / 200;            // [B,100,2]
    const int blocks = (B + SAMPLES_PER_BLOCK - 1) / SAMPLES_PER_BLOCK;

    scorenet_fused<<<blocks, 256, 0, stream>>>(
        x, t, Wf, embW, embB, W1, b1, W2a, b2a, W2b, b2b, W2c, b2c,
        (float*)d_out, B);
}